// Round 4
// baseline (183.594 us; speedup 1.0000x reference)
//
#include <hip/hip_runtime.h>

#define PI_F 3.14159f

typedef _Float16 f16;
typedef __attribute__((ext_vector_type(8))) _Float16 f16x8;
typedef __attribute__((ext_vector_type(4))) _Float16 f16x4;
typedef __attribute__((ext_vector_type(4))) float f32x4;

// ---------------------------------------------------------------------------
// prep: head-organized weights Wt[1024][2048] fp16 (64 heads x 16 padded cols,
// pads exactly zero) + bias bh[1024] f32 (pads zero). 16-col head granule =
// one MFMA n-fragment.
// ---------------------------------------------------------------------------
__global__ void prep_kernel(const float* __restrict__ W_syn, const float* __restrict__ b_syn,
                            const float* __restrict__ W_sem, const float* __restrict__ b_sem,
                            const float* __restrict__ W_nar, const float* __restrict__ b_nar,
                            f16* __restrict__ Wt, float* __restrict__ bh)
{
    const int p = blockIdx.x;            // padded col 0..1023
    const int h = p >> 4, c = p & 15;
    const float* W; const float* bb; int ld, sc;
    if (h < 10)      { W = W_syn; bb = b_syn; ld = 100; sc = (c < 10) ? h*10 + c : -1; }
    else if (h < 40) { W = W_sem; bb = b_sem; ld = 450; sc = (c < 15) ? (h-10)*15 + c : -1; }
    else             { W = W_nar; bb = b_nar; ld = 360; sc = (c < 15) ? (h-40)*15 + c : -1; }
    for (int k = (int)threadIdx.x; k < 2048; k += (int)blockDim.x)
        Wt[(size_t)p*2048 + k] = (sc >= 0) ? (f16)W[(size_t)k*ld + sc] : (f16)0.0f;
    if (threadIdx.x == 0) bh[p] = (sc >= 0) ? bb[sc] : 0.0f;
}

// ---------------------------------------------------------------------------
// gemm_fused: per 128x128 tile (128 tokens x 8 heads), MFMA K-loop, then
// acc -> LDS (fp16, reusing staging buffers), then per-(token,head) rotor-exp
// epilogue with direct fp32 output writes (all 32 slots, zeros included).
// ---------------------------------------------------------------------------
__global__ __launch_bounds__(256)
void gemm_fused_kernel(const float* __restrict__ X, const f16* __restrict__ Wt,
                       const float* __restrict__ bh, float* __restrict__ Out)
{
    constexpr int LDT = 72;    // staging row stride (144B = 9*16B)
    constexpr int CLD = 136;   // C row stride (272B = 17*16B)
    __shared__ f16 smem[2 * 128 * LDT];                 // 36,864 B
    f16 (*As)[LDT] = (f16(*)[LDT])smem;
    f16 (*Bs)[LDT] = (f16(*)[LDT])(smem + 128 * LDT);
    f16 (*Cs)[CLD] = (f16(*)[CLD])smem;                 // reused after K-loop (34,816 B)

    const int tid  = threadIdx.x;
    // XCD-chunked swizzle: XCD r owns bm-panels [16r,16r+16), all 8 bn of a bm
    // consecutive -> X M-panel stays in one L2.
    const int sw   = (blockIdx.x & 7) * 128 + (blockIdx.x >> 3);
    const int bm   = sw >> 3, bn = sw & 7;
    const int m0   = bm * 128, n0 = bn * 128;
    const int wave = tid >> 6, lane = tid & 63;
    const int wr   = (wave >> 1) * 64, wc = (wave & 1) * 64;
    const int l15  = lane & 15, l4 = lane >> 4;

    const int arow = tid >> 4;             // A stage: 16 rows/pass, 8 passes
    const int acol = (tid & 15) * 4;

    int brow[4], bcol[4];                  // B stage: 4 x 16B chunks/thread
#pragma unroll
    for (int j = 0; j < 4; ++j) {
        const int c = tid + 256 * j;
        brow[j] = c >> 3; bcol[j] = (c & 7) * 8;
    }

    f32x4 acc[4][4] = {};
    float4 areg[8];
    f16x8  breg[4];

    const float* xa = X + (size_t)(m0 + arow) * 2048 + acol;
#pragma unroll
    for (int it = 0; it < 8; ++it)
        areg[it] = *(const float4*)(xa + (size_t)it * 16 * 2048);
#pragma unroll
    for (int j = 0; j < 4; ++j)
        breg[j] = *(const f16x8*)(Wt + (size_t)(n0 + brow[j]) * 2048 + bcol[j]);

    for (int kt = 0; kt < 32; ++kt) {
        __syncthreads();
#pragma unroll
        for (int it = 0; it < 8; ++it) {
            f16x4 v;
            v.x = (f16)areg[it].x; v.y = (f16)areg[it].y;
            v.z = (f16)areg[it].z; v.w = (f16)areg[it].w;
            *(f16x4*)&As[arow + it*16][acol] = v;
        }
#pragma unroll
        for (int j = 0; j < 4; ++j)
            *(f16x8*)&Bs[brow[j]][bcol[j]] = breg[j];
        __syncthreads();
        if (kt < 31) {                     // prefetch next K-tile (overlaps MFMA)
            const int k0 = (kt + 1) * 64;
            const float* xn = xa + k0;
#pragma unroll
            for (int it = 0; it < 8; ++it)
                areg[it] = *(const float4*)(xn + (size_t)it * 16 * 2048);
#pragma unroll
            for (int j = 0; j < 4; ++j)
                breg[j] = *(const f16x8*)(Wt + (size_t)(n0 + brow[j]) * 2048 + k0 + bcol[j]);
        }
#pragma unroll
        for (int ks = 0; ks < 2; ++ks) {
            f16x8 af[4], bfr[4];
#pragma unroll
            for (int mf = 0; mf < 4; ++mf)
                af[mf] = *(const f16x8*)&As[wr + mf*16 + l15][ks*32 + l4*8];
#pragma unroll
            for (int nf = 0; nf < 4; ++nf)
                bfr[nf] = *(const f16x8*)&Bs[wc + nf*16 + l15][ks*32 + l4*8];
#pragma unroll
            for (int mf = 0; mf < 4; ++mf)
#pragma unroll
                for (int nf = 0; nf < 4; ++nf)
                    acc[mf][nf] = __builtin_amdgcn_mfma_f32_16x16x32_f16(af[mf], bfr[nf], acc[mf][nf], 0, 0, 0);
        }
    }

    // ---- acc -> LDS (C/D layout: col=lane&15, row=(lane>>4)*4+reg) ----
    __syncthreads();                       // all MFMA LDS reads done before reuse
#pragma unroll
    for (int mf = 0; mf < 4; ++mf)
#pragma unroll
        for (int nf = 0; nf < 4; ++nf)
#pragma unroll
            for (int r = 0; r < 4; ++r)
                Cs[wr + mf*16 + l4*4 + r][wc + nf*16 + l15] = (f16)acc[mf][nf][r];
    __syncthreads();

    // ---- fused epilogue: 4 (token,head) pairs per thread ----
#pragma unroll
    for (int p = 0; p < 4; ++p) {
        const int linear = p * 256 + tid;          // 0..1023
        const int t  = linear >> 3;                // token-in-tile 0..127
        const int hh = linear & 7;                 // head-in-tile 0..7
        const int H  = bn * 8 + hh;                // global head 0..63
        f16x8 y0 = *(const f16x8*)&Cs[t][hh * 16];
        f16x8 y1 = *(const f16x8*)&Cs[t][hh * 16 + 8];
        const float* bb = bh + H * 16;

        float Bv[16];
#pragma unroll
        for (int j = 0; j < 8; ++j) {
            Bv[j]     = tanhf((float)y0[j] + bb[j])     * PI_F;
            Bv[j + 8] = tanhf((float)y1[j] + bb[j + 8]) * PI_F;
        }
        float s2 = 0.f;
#pragma unroll
        for (int j = 0; j < 16; ++j) s2 += Bv[j] * Bv[j];
        const float theta = 0.5f * sqrtf(s2);
        const float sinc  = (theta > 1e-8f) ? (sinf(theta) / theta) : 1.0f;
        const float cs    = cosf(theta);
        const float scale = -0.5f * sinc;
        float C[16];
#pragma unroll
        for (int j = 0; j < 16; ++j) C[j] = Bv[j] * scale;

        float4 v0 = {0,0,0,0}, v1 = {0,0,0,0}, v2 = {0,0,0,0}, v3 = {0,0,0,0};
        float4 v4 = {0,0,0,0}, v5 = {0,0,0,0}, v6 = {0,0,0,0}, v7 = {0,0,0,0};
        v0.x = cs;                                 // scalar slot 0
        if (H < 10) {                              // syn: biv 6..15
            v1.z=C[0]; v1.w=C[1];
            v2.x=C[2]; v2.y=C[3]; v2.z=C[4]; v2.w=C[5];
            v3.x=C[6]; v3.y=C[7]; v3.z=C[8]; v3.w=C[9];
        } else if (H < 40) {                       // sem: vec 1..5 + biv 6..15
            v0.y=C[0]; v0.z=C[1]; v0.w=C[2];
            v1.x=C[3]; v1.y=C[4]; v1.z=C[5]; v1.w=C[6];
            v2.x=C[7]; v2.y=C[8]; v2.z=C[9]; v2.w=C[10];
            v3.x=C[11]; v3.y=C[12]; v3.z=C[13]; v3.w=C[14];
        } else {                                   // nar: biv 6..15 + quad 26..30
            v1.z=C[0]; v1.w=C[1];
            v2.x=C[2]; v2.y=C[3]; v2.z=C[4]; v2.w=C[5];
            v3.x=C[6]; v3.y=C[7]; v3.z=C[8]; v3.w=C[9];
            v6.z=C[10]; v6.w=C[11];
            v7.x=C[12]; v7.y=C[13]; v7.z=C[14];
        }
        float4* dst = (float4*)(Out + ((size_t)(m0 + t) * 64 + H) * 32);
        dst[0]=v0; dst[1]=v1; dst[2]=v2; dst[3]=v3;
        dst[4]=v4; dst[5]=v5; dst[6]=v6; dst[7]=v7;
    }
}

// ---------------------------------------------------------------------------
extern "C" void kernel_launch(void* const* d_in, const int* in_sizes, int n_in,
                              void* d_out, int out_size, void* d_ws, size_t ws_size,
                              hipStream_t stream)
{
    const float* x     = (const float*)d_in[0];
    const float* W_syn = (const float*)d_in[1];
    const float* b_syn = (const float*)d_in[2];
    const float* W_sem = (const float*)d_in[3];
    const float* b_sem = (const float*)d_in[4];
    const float* W_nar = (const float*)d_in[5];
    const float* b_nar = (const float*)d_in[6];

    // ws: Wt fp16 4MB | bh f32 4KB  => 4.2MB total
    f16*   Wt = (f16*)d_ws;
    float* bh = (float*)((char*)d_ws + (size_t)4*1024*1024);
    float* Out = (float*)d_out;

    prep_kernel<<<1024, 256, 0, stream>>>(W_syn, b_syn, W_sem, b_sem, W_nar, b_nar, Wt, bh);
    gemm_fused_kernel<<<1024, 256, 0, stream>>>(x, Wt, bh, Out);
}

// Round 5
// 173.894 us; speedup vs baseline: 1.0558x; 1.0558x over previous
//
#include <hip/hip_runtime.h>

#define PI_F 3.14159f

typedef _Float16 f16;
typedef __attribute__((ext_vector_type(8))) _Float16 f16x8;
typedef __attribute__((ext_vector_type(4))) _Float16 f16x4;
typedef __attribute__((ext_vector_type(4))) float f32x4;

// ---------------------------------------------------------------------------
// prep: Wt[1024][2048] fp16, head-organized (64 heads x 16 padded cols, pads
// exactly 0) + bh[1024] f32. LDS-transposed so BOTH global sides are coalesced:
// block = (head h, k-chunk of 64). Read W[k][c] coalesced -> tile[c][k] ->
// write Wt rows (128B contiguous per row) coalesced.
// ---------------------------------------------------------------------------
__global__ void prep_kernel(const float* __restrict__ W_syn, const float* __restrict__ b_syn,
                            const float* __restrict__ W_sem, const float* __restrict__ b_sem,
                            const float* __restrict__ W_nar, const float* __restrict__ b_nar,
                            f16* __restrict__ Wt, float* __restrict__ bh)
{
    __shared__ float tile[16][65];               // 65: column-write bank spread
    const int blk = blockIdx.x;                  // 0..2047
    const int h = blk >> 5, k0 = (blk & 31) * 64;
    const float* W; const float* bb; int ld, base, width;
    if (h < 10)      { W = W_syn; bb = b_syn; ld = 100; base = h*10;      width = 10; }
    else if (h < 40) { W = W_sem; bb = b_sem; ld = 450; base = (h-10)*15; width = 15; }
    else             { W = W_nar; bb = b_nar; ld = 360; base = (h-40)*15; width = 15; }
    const int tid = threadIdx.x;
    {
        const int c = tid & 15, kr = tid >> 4;   // lanes: c fastest -> coalesced reads
        if (c < width)
#pragma unroll
            for (int ii = 0; ii < 4; ++ii)
                tile[c][kr + ii*16] = W[(size_t)(k0 + kr + ii*16) * ld + base + c];
    }
    __syncthreads();
    {
        const int c = tid >> 4, kq = (tid & 15) * 4;  // lanes: kq fastest -> coalesced writes
        f16x4 v;
#pragma unroll
        for (int q = 0; q < 4; ++q)
            v[q] = (c < width) ? (f16)tile[c][kq + q] : (f16)0.0f;
        *(f16x4*)(Wt + (size_t)(h*16 + c) * 2048 + k0 + kq) = v;
    }
    if ((blk & 31) == 0 && tid < 16)
        bh[h*16 + tid] = (tid < width) ? bb[base + tid] : 0.0f;
}

// ---------------------------------------------------------------------------
// gemm_fused: 128x128 tile (128 tokens x 8 heads), BK=64, 4 waves.
// A: fp32 X -> LDS via global_load_lds w16 (cvt fp16 at read time).
// B: fp16 Wt -> LDS via global_load_lds w16.
// T2 XOR swizzle, both-sides: linear LDS dest, source 16B-chunk index XORed
// with row bits; ds_read applies the same XOR -> conflict-free reads.
// Then fused rotor-exp epilogue via LDS C-staging, fp32 output.
// ---------------------------------------------------------------------------
__global__ __launch_bounds__(256)
void gemm_fused_kernel(const float* __restrict__ X, const f16* __restrict__ Wt,
                       const float* __restrict__ bh, float* __restrict__ Out)
{
    __shared__ __align__(16) char smem[49152];     // 48 KB -> 3 blocks/CU
    float* Asf = (float*)smem;                     // [128 rows][16 chunks of 4 f32]
    f16*   Bsh = (f16*)(smem + 32768);             // [128 rows][8 chunks of 8 f16]
    f16 (*Cs)[136] = (f16(*)[136])smem;            // reused post-K-loop (34.8 KB)

    const int tid  = threadIdx.x;
    // XCD-chunked swizzle: XCD r owns bm-panels [16r,16r+16); 8 bn of a bm
    // consecutive -> X M-panel stays in one XCD L2. nwg=1024, %8==0 (bijective).
    const int sw   = (blockIdx.x & 7) * 128 + (blockIdx.x >> 3);
    const int bm   = sw >> 3, bn = sw & 7;
    const int m0   = bm * 128, n0 = bn * 128;
    const int wave = tid >> 6, lane = tid & 63;
    const int wr   = (wave >> 1) * 64, wc = (wave & 1) * 64;
    const int l15  = lane & 15, l4 = lane >> 4;

    f32x4 acc[4][4] = {};

    for (int kt = 0; kt < 32; ++kt) {
        const int kof = kt * 64;
        // ---- stage A: 2048 16B-chunks, linear LDS, source chunk-XORed ----
#pragma unroll
        for (int i = 0; i < 8; ++i) {
            const int ac = (wave*8 + i)*64 + lane;          // LDS chunk index
            const int ar = ac >> 4;
            const int agc = (ac & 15) ^ (ar & 15);          // swizzled k-slice
            const float* src = X + (size_t)(m0 + ar) * 2048 + kof + agc * 4;
            __builtin_amdgcn_global_load_lds(
                (const __attribute__((address_space(1))) void*)src,
                (__attribute__((address_space(3))) void*)(smem + (wave*8 + i) * 1024),
                16, 0, 0);
        }
        // ---- stage B: 1024 16B-chunks ----
#pragma unroll
        for (int i = 0; i < 4; ++i) {
            const int bc = (wave*4 + i)*64 + lane;
            const int br = bc >> 3;
            const int bgc = (bc & 7) ^ (br & 7);
            const f16* src = Wt + (size_t)(n0 + br) * 2048 + kof + bgc * 8;
            __builtin_amdgcn_global_load_lds(
                (const __attribute__((address_space(1))) void*)src,
                (__attribute__((address_space(3))) void*)(smem + 32768 + (wave*4 + i) * 1024),
                16, 0, 0);
        }
        __syncthreads();                 // compiler drains vmcnt before s_barrier
#pragma unroll
        for (int ks = 0; ks < 2; ++ks) {
            f16x8 af[4], bf[4];
#pragma unroll
            for (int mf = 0; mf < 4; ++mf) {
                const int r  = wr + mf*16 + l15;
                const int j0 = ks*8 + l4*2;                 // 16B-slice index (fp32)
                const float4 lo = *(const float4*)(Asf + ((size_t)r*16 + ( j0      ^ (r & 15))) * 4);
                const float4 hi = *(const float4*)(Asf + ((size_t)r*16 + ((j0 + 1) ^ (r & 15))) * 4);
                f16x8 a;
                a[0]=(f16)lo.x; a[1]=(f16)lo.y; a[2]=(f16)lo.z; a[3]=(f16)lo.w;
                a[4]=(f16)hi.x; a[5]=(f16)hi.y; a[6]=(f16)hi.z; a[7]=(f16)hi.w;
                af[mf] = a;
            }
#pragma unroll
            for (int nf = 0; nf < 4; ++nf) {
                const int r = wc + nf*16 + l15;
                const int j = ks*4 + l4;                    // 16B-slice index (fp16)
                bf[nf] = *(const f16x8*)(Bsh + ((size_t)r*8 + (j ^ (r & 7))) * 8);
            }
#pragma unroll
            for (int mf = 0; mf < 4; ++mf)
#pragma unroll
                for (int nf = 0; nf < 4; ++nf)
                    acc[mf][nf] = __builtin_amdgcn_mfma_f32_16x16x32_f16(af[mf], bf[nf], acc[mf][nf], 0, 0, 0);
        }
        __syncthreads();                 // LDS free before next kt's DMA
    }

    // ---- acc -> LDS (C/D: col=lane&15, row=(lane>>4)*4+reg) ----
#pragma unroll
    for (int mf = 0; mf < 4; ++mf)
#pragma unroll
        for (int nf = 0; nf < 4; ++nf)
#pragma unroll
            for (int r = 0; r < 4; ++r)
                Cs[wr + mf*16 + l4*4 + r][wc + nf*16 + l15] = (f16)acc[mf][nf][r];
    __syncthreads();

    // ---- fused epilogue: 4 (token,head) pairs per thread ----
#pragma unroll
    for (int p = 0; p < 4; ++p) {
        const int linear = p * 256 + tid;          // 0..1023
        const int t  = linear >> 3;                // token-in-tile
        const int hh = linear & 7;                 // head-in-tile
        const int H  = bn * 8 + hh;                // global head
        f16x8 y0 = *(const f16x8*)&Cs[t][hh * 16];
        f16x8 y1 = *(const f16x8*)&Cs[t][hh * 16 + 8];
        const float* bb = bh + H * 16;

        float Bv[16];
#pragma unroll
        for (int j = 0; j < 8; ++j) {
            Bv[j]     = tanhf((float)y0[j] + bb[j])     * PI_F;
            Bv[j + 8] = tanhf((float)y1[j] + bb[j + 8]) * PI_F;
        }
        float s2 = 0.f;
#pragma unroll
        for (int j = 0; j < 16; ++j) s2 += Bv[j] * Bv[j];
        const float theta = 0.5f * sqrtf(s2);
        const float sinc  = (theta > 1e-8f) ? (sinf(theta) / theta) : 1.0f;
        const float cs    = cosf(theta);
        const float scale = -0.5f * sinc;
        float C[16];
#pragma unroll
        for (int j = 0; j < 16; ++j) C[j] = Bv[j] * scale;

        float4 v0 = {0,0,0,0}, v1 = {0,0,0,0}, v2 = {0,0,0,0}, v3 = {0,0,0,0};
        float4 v4 = {0,0,0,0}, v5 = {0,0,0,0}, v6 = {0,0,0,0}, v7 = {0,0,0,0};
        v0.x = cs;                                 // scalar slot 0
        if (H < 10) {                              // syn: biv 6..15
            v1.z=C[0]; v1.w=C[1];
            v2.x=C[2]; v2.y=C[3]; v2.z=C[4]; v2.w=C[5];
            v3.x=C[6]; v3.y=C[7]; v3.z=C[8]; v3.w=C[9];
        } else if (H < 40) {                       // sem: vec 1..5 + biv 6..15
            v0.y=C[0]; v0.z=C[1]; v0.w=C[2];
            v1.x=C[3]; v1.y=C[4]; v1.z=C[5]; v1.w=C[6];
            v2.x=C[7]; v2.y=C[8]; v2.z=C[9]; v2.w=C[10];
            v3.x=C[11]; v3.y=C[12]; v3.z=C[13]; v3.w=C[14];
        } else {                                   // nar: biv 6..15 + quad 26..30
            v1.z=C[0]; v1.w=C[1];
            v2.x=C[2]; v2.y=C[3]; v2.z=C[4]; v2.w=C[5];
            v3.x=C[6]; v3.y=C[7]; v3.z=C[8]; v3.w=C[9];
            v6.z=C[10]; v6.w=C[11];
            v7.x=C[12]; v7.y=C[13]; v7.z=C[14];
        }
        float4* dst = (float4*)(Out + ((size_t)(m0 + t) * 64 + H) * 32);
        dst[0]=v0; dst[1]=v1; dst[2]=v2; dst[3]=v3;
        dst[4]=v4; dst[5]=v5; dst[6]=v6; dst[7]=v7;
    }
}

// ---------------------------------------------------------------------------
extern "C" void kernel_launch(void* const* d_in, const int* in_sizes, int n_in,
                              void* d_out, int out_size, void* d_ws, size_t ws_size,
                              hipStream_t stream)
{
    const float* x     = (const float*)d_in[0];
    const float* W_syn = (const float*)d_in[1];
    const float* b_syn = (const float*)d_in[2];
    const float* W_sem = (const float*)d_in[3];
    const float* b_sem = (const float*)d_in[4];
    const float* W_nar = (const float*)d_in[5];
    const float* b_nar = (const float*)d_in[6];

    // ws: Wt fp16 4MB | bh f32 4KB  => 4.2MB total (known-safe footprint)
    f16*   Wt = (f16*)d_ws;
    float* bh = (float*)((char*)d_ws + (size_t)4*1024*1024);
    float* Out = (float*)d_out;

    prep_kernel<<<2048, 256, 0, stream>>>(W_syn, b_syn, W_sem, b_sem, W_nar, b_nar, Wt, bh);
    gemm_fused_kernel<<<1024, 256, 0, stream>>>(x, Wt, bh, Out);
}